// Round 2
// 407.119 us; speedup vs baseline: 1.0126x; 1.0126x over previous
//
#include <hip/hip_runtime.h>
#include <hip/hip_bf16.h>

#define T_LEN 8192
#define D_HID 2048
#define ND    8192

// d_ws layout
#define WS_FLAG  0      // int: 1 = arrays fp32, 0 = bf16
#define WS_ALPHA 16     // 3 floats: apre, apost, ares
#define WS_BIAS  64     // 24 floats: bpre[4], bpost[4], bres[16]
#define WS_W     256    // 24 x 8192 bf16 packed weights (pre0..3, post0..3, res0..15)

typedef __attribute__((ext_vector_type(8))) short bf16x8;
typedef __attribute__((ext_vector_type(4))) float f32x4;

__device__ __forceinline__ float bf2f(unsigned int h) {
    union { unsigned int u; float f; } v;
    v.u = h << 16;
    return v.f;
}

__device__ __forceinline__ unsigned int f2bf(float f) {
    union { float f; unsigned int u; } v;
    v.f = f;
    unsigned int r = v.u + 0x7fffu + ((v.u >> 16) & 1u);  // RNE
    return r >> 16;
}

__device__ __forceinline__ float ssq8(uint4 v) {
    float s = 0.f;
    unsigned int ws[4] = {v.x, v.y, v.z, v.w};
#pragma unroll
    for (int i = 0; i < 4; ++i) {
        float a = bf2f(ws[i] & 0xffffu);
        float b = bf2f(ws[i] >> 16);
        s = fmaf(a, a, s);
        s = fmaf(b, b, s);
    }
    return s;
}

__device__ __forceinline__ float d4(float4 a) {
    return fmaf(a.x, a.x, fmaf(a.y, a.y, fmaf(a.z, a.z, a.w * a.w)));
}

__device__ __forceinline__ uint4 pack8(float4 a, float4 b) {
    uint4 r;
    r.x = f2bf(a.x) | (f2bf(a.y) << 16);
    r.y = f2bf(a.z) | (f2bf(a.w) << 16);
    r.z = f2bf(b.x) | (f2bf(b.y) << 16);
    r.w = f2bf(b.z) | (f2bf(b.w) << 16);
    return r;
}

// scalar dtype sniff (alphas may be fp32 even when arrays are bf16):
// bf16-read sane -> bf16, else fp32.
__device__ __forceinline__ float rd_alpha(const void* p) {
    float v = bf2f(*(const unsigned short*)p);
    float av = fabsf(v);
    if (av > 1e-6f && av < 64.f) return v;
    return *(const float*)p;
}

// ---------------------------------------------------------------------------
// prep: sniff array dtype, pack all 24 weight rows to bf16 in d_ws, stash
// flag + alphas + biases (as fp32) in a small header. 96 blocks x 256 thr,
// 8 elems/thread covers 24*8192.
// ---------------------------------------------------------------------------
__global__ __launch_bounds__(256)
void prep_kern(const void* __restrict__ xs_,
               const void* __restrict__ Wpre_, const void* __restrict__ Wpost_,
               const void* __restrict__ Wres_,
               const void* __restrict__ bpre_, const void* __restrict__ bpost_,
               const void* __restrict__ bres_,
               const void* __restrict__ apre_, const void* __restrict__ apost_,
               const void* __restrict__ ares_, void* __restrict__ ws_)
{
    __shared__ int insane;
    const int tid = threadIdx.x;

    if (tid == 0) insane = 0;
    __syncthreads();
    if (tid < 128) {
        const unsigned short* p = (tid < 64) ? (const unsigned short*)Wpre_
                                             : (const unsigned short*)xs_;
        float m = fabsf(bf2f(p[tid & 63]));
        if (!(m < 64.0f)) atomicOr(&insane, 1);  // catches inf/NaN too
    }
    __syncthreads();
    const bool fp32 = (insane != 0);

    if (blockIdx.x == 0) {
        if (tid == 0) {
            *(int*)ws_ = fp32 ? 1 : 0;
            float* al = (float*)((char*)ws_ + WS_ALPHA);
            al[0] = rd_alpha(apre_);
            al[1] = rd_alpha(apost_);
            al[2] = rd_alpha(ares_);
        }
        if (tid < 24) {
            const void* b = (tid < 4) ? bpre_ : (tid < 8) ? bpost_ : bres_;
            const int i = (tid < 4) ? tid : (tid < 8) ? tid - 4 : tid - 8;
            float v = fp32 ? ((const float*)b)[i]
                           : bf2f(((const unsigned short*)b)[i]);
            ((float*)((char*)ws_ + WS_BIAS))[tid] = v;
        }
    }

    const int g = blockIdx.x * 2048 + tid * 8;   // packed element index
    const int row = g >> 13, e = g & 8191;
    const void* base = (row < 4) ? Wpre_ : (row < 8) ? Wpost_ : Wres_;
    const int srow = (row < 4) ? row : (row < 8) ? row - 4 : row - 8;
    unsigned short* dst = (unsigned short*)((char*)ws_ + WS_W) + g;
    if (fp32) {
        const float* p = (const float*)base + (size_t)srow * ND + e;
        *(uint4*)dst = pack8(*(const float4*)p, *(const float4*)(p + 4));
    } else {
        *(uint4*)dst = *(const uint4*)((const unsigned short*)base + (size_t)srow * ND + e);
    }
}

// ---------------------------------------------------------------------------
// main: one block = 16 t-rows, 4 waves split K. Per round: stage 16t x 256e
// bf16 into double-buffered LDS (sumsq for free), 2 MFMA k-steps/wave,
// B-frags are pre-packed bf16 straight from L2-resident d_ws.
// ---------------------------------------------------------------------------
template <int AFP32>
__device__ __forceinline__ void main_body(
    const void* __restrict__ xs_, const unsigned short* __restrict__ wsW,
    const float* __restrict__ al, const float* __restrict__ bs,
    void* __restrict__ out_,
    unsigned short* a_lds, float* c_red, float* ss_red)
{
    const int tid = threadIdx.x;
    const int w = tid >> 6, lane = tid & 63, quad = lane >> 4, l15 = lane & 15;
    const int t0 = blockIdx.x * 16;
    const int t_l = (tid >> 3) & 15, es = tid & 7, s0 = tid >> 7, s1 = s0 + 2;

    const size_t row0 = (size_t)(s0 * T_LEN + t0 + t_l) * D_HID + es * 8;
    const size_t row1 = (size_t)(s1 * T_LEN + t0 + t_l) * D_HID + es * 8;
    const int lofs0 = t_l * 264 + s0 * 64 + es * 8;
    const int lofs1 = t_l * 264 + s1 * 64 + es * 8;

    // acc0 cols 0..15 <-> packed rows 0..15 (pre0-3, post0-3, res0-7)
    // acc1 cols 0..7  <-> packed rows 16..23 (res8-15); cols 8..15 unused junk
    const unsigned short* brow0 = wsW + (size_t)l15 * ND;
    const unsigned short* brow1 = wsW + (size_t)(16 + (l15 & 7)) * ND;

    f32x4 acc0 = {0.f, 0.f, 0.f, 0.f};
    f32x4 acc1 = {0.f, 0.f, 0.f, 0.f};
    float ss = 0.f;

    const unsigned short* gp0; const unsigned short* gp1;
    const float* gf0; const float* gf1;
    uint4 cur0, cur1;
    float4 f0a, f0b, f1a, f1b;
    if constexpr (AFP32) {
        gf0 = (const float*)xs_ + row0;  gf1 = (const float*)xs_ + row1;
        f0a = *(const float4*)gf0;  f0b = *(const float4*)(gf0 + 4);
        f1a = *(const float4*)gf1;  f1b = *(const float4*)(gf1 + 4);
    } else {
        gp0 = (const unsigned short*)xs_ + row0;  gp1 = (const unsigned short*)xs_ + row1;
        cur0 = *(const uint4*)gp0;  cur1 = *(const uint4*)gp1;
    }

    for (int r = 0; r < 32; ++r) {
        unsigned short* lb = a_lds + (r & 1) * (16 * 264);
        uint4 w0, w1;
        if constexpr (AFP32) {
            ss += d4(f0a) + d4(f0b) + d4(f1a) + d4(f1b);
            w0 = pack8(f0a, f0b);  w1 = pack8(f1a, f1b);
        } else {
            ss += ssq8(cur0) + ssq8(cur1);
            w0 = cur0;  w1 = cur1;
        }
        *(uint4*)(lb + lofs0) = w0;
        *(uint4*)(lb + lofs1) = w1;
        if (r < 31) {  // prefetch stays in flight across barrier + MFMA phase
            if constexpr (AFP32) {
                const float* p0 = gf0 + (r + 1) * 64;
                const float* p1 = gf1 + (r + 1) * 64;
                f0a = *(const float4*)p0;  f0b = *(const float4*)(p0 + 4);
                f1a = *(const float4*)p1;  f1b = *(const float4*)(p1 + 4);
            } else {
                cur0 = *(const uint4*)(gp0 + (r + 1) * 64);
                cur1 = *(const uint4*)(gp1 + (r + 1) * 64);
            }
        }
        __syncthreads();  // buf[r&1] visible; double-buffer -> no tail barrier
        const unsigned short* ar = lb + l15 * 264 + w * 64 + quad * 8;
#pragma unroll
        for (int kk = 0; kk < 2; ++kk) {
            const bf16x8 af = *(const bf16x8*)(ar + kk * 32);
            const int e = w * 2048 + quad * 8 + r * 64 + kk * 32;
            const uint4 br0 = *(const uint4*)(brow0 + e);
            const uint4 br1 = *(const uint4*)(brow1 + e);
            acc0 = __builtin_amdgcn_mfma_f32_16x16x32_bf16(
                af, __builtin_bit_cast(bf16x8, br0), acc0, 0, 0, 0);
            acc1 = __builtin_amdgcn_mfma_f32_16x16x32_bf16(
                af, __builtin_bit_cast(bf16x8, br1), acc1, 0, 0, 0);
        }
    }

    // split-K reduction staging
    ss_red[tid] = ss;
    {
        float* cw = c_red + w * (16 * 33);
#pragma unroll
        for (int g = 0; g < 4; ++g) {   // C/D: col=l15 (n), row=quad*4+g (m)
            cw[(quad * 4 + g) * 33 + l15]      = acc0[g];
            cw[(quad * 4 + g) * 33 + 16 + l15] = acc1[g];
        }
    }
    __syncthreads();

    if (tid < 16) {
        const int t = tid;
        float sst = 0.f;
#pragma unroll
        for (int h = 0; h < 2; ++h)
#pragma unroll
            for (int e = 0; e < 8; ++e)
                sst += ss_red[h * 128 + t * 8 + e];
        const float rinv = rsqrtf(sst * (1.0f / (float)ND) + 1e-8f);

        float dots[24];
#pragma unroll
        for (int n = 0; n < 24; ++n)
            dots[n] = c_red[0 * 528 + t * 33 + n] + c_red[1 * 528 + t * 33 + n]
                    + c_red[2 * 528 + t * 33 + n] + c_red[3 * 528 + t * 33 + n];

        const float apre = al[0], apost = al[1], ares = al[2];
        const size_t tg = (size_t)t0 + t;

        float hpre[4], hpost[4], M[16];
#pragma unroll
        for (int k = 0; k < 4; ++k) {
            const float zp = fmaf(apre * dots[k], rinv, bs[k]);
            hpre[k] = 1.0f / (1.0f + __expf(-zp));
            const float zq = fmaf(apost * dots[4 + k], rinv, bs[4 + k]);
            hpost[k] = 2.0f / (1.0f + __expf(-zq));
        }
#pragma unroll
        for (int m = 0; m < 16; ++m)
            M[m] = __expf(fmaf(ares * dots[8 + m], rinv, bs[8 + m]));

        for (int it = 0; it < 20; ++it) {
#pragma unroll
            for (int i = 0; i < 4; ++i) {
                const float rr = 1.0f / ((M[i*4+0] + M[i*4+1]) + (M[i*4+2] + M[i*4+3]));
                M[i*4+0] *= rr; M[i*4+1] *= rr; M[i*4+2] *= rr; M[i*4+3] *= rr;
            }
#pragma unroll
            for (int j = 0; j < 4; ++j) {
                const float cr = 1.0f / ((M[j] + M[4+j]) + (M[8+j] + M[12+j]));
                M[j] *= cr; M[4+j] *= cr; M[8+j] *= cr; M[12+j] *= cr;
            }
        }

        if constexpr (AFP32) {
            float* out = (float*)out_;
#pragma unroll
            for (int m = 0; m < 16; ++m) out[tg * 16 + m] = M[m];
#pragma unroll
            for (int k = 0; k < 4; ++k) {
                out[(size_t)T_LEN * 16 + tg * 4 + k] = hpre[k];
                out[(size_t)T_LEN * 20 + tg * 4 + k] = hpost[k];
            }
        } else {
            unsigned short* out = (unsigned short*)out_;
#pragma unroll
            for (int m = 0; m < 16; ++m) out[tg * 16 + m] = (unsigned short)f2bf(M[m]);
#pragma unroll
            for (int k = 0; k < 4; ++k) {
                out[(size_t)T_LEN * 16 + tg * 4 + k] = (unsigned short)f2bf(hpre[k]);
                out[(size_t)T_LEN * 20 + tg * 4 + k] = (unsigned short)f2bf(hpost[k]);
            }
        }
    }
}

__global__ __launch_bounds__(256, 2)
void mhc_main(const void* __restrict__ xs_, void* __restrict__ out_,
              const void* __restrict__ ws_)
{
    __shared__ __align__(16) unsigned short a_lds[2 * 16 * 264];  // double-buffered
    __shared__ float c_red[4 * 16 * 33];
    __shared__ float ss_red[256];

    const char* ws = (const char*)ws_;
    const int flag = *(const int*)(ws + WS_FLAG);  // uniform scalar branch
    const unsigned short* wsW = (const unsigned short*)(ws + WS_W);
    const float* al = (const float*)(ws + WS_ALPHA);
    const float* bs = (const float*)(ws + WS_BIAS);

    if (flag) main_body<1>(xs_, wsW, al, bs, out_, a_lds, c_red, ss_red);
    else      main_body<0>(xs_, wsW, al, bs, out_, a_lds, c_red, ss_red);
}

extern "C" void kernel_launch(void* const* d_in, const int* in_sizes, int n_in,
                              void* d_out, int out_size, void* d_ws, size_t ws_size,
                              hipStream_t stream)
{
    // prep: 96 blocks * 256 thr * 8 elems = 24*8192 packed weight elements
    prep_kern<<<dim3(96), dim3(256), 0, stream>>>(
        d_in[0], d_in[1], d_in[2], d_in[3], d_in[4], d_in[5], d_in[6],
        d_in[7], d_in[8], d_in[9], d_ws);
    mhc_main<<<dim3(T_LEN / 16), dim3(256), 0, stream>>>(d_in[0], d_out, d_ws);
}